// Round 1
// baseline (67.479 us; speedup 1.0000x reference)
//
#include <hip/hip_runtime.h>
#include <hip/hip_bf16.h>

#define HW 9216
#define CDIM 128
#define BM 128
#define BN 128
#define LDP (CDIM + 8)          // padded LDS row stride (bf16 elems): 272B rows -> 2-way bank alias max
#define NBLK ((HW / BM) * (HW / BN))   // 72*72 = 5184

using bf16 = __hip_bfloat16;
typedef __attribute__((ext_vector_type(4))) float f32x4;
typedef __attribute__((ext_vector_type(8))) short s16x8;

// exp(d / 0.04) = exp2(d * log2(e)/0.04)
#define EXP_SCALE 36.067376022224085f

// ---------------------------------------------------------------------------
// Kernel 1: x[b] layout [C][HW] f32  ->  feat[b] layout [HW][C] bf16
// 64x64 LDS tile transpose. grid = (HW/64, C/64, 2), block = 256.
// ---------------------------------------------------------------------------
__global__ __launch_bounds__(256) void prep_kernel(const float* __restrict__ x,
                                                   bf16* __restrict__ feat) {
    __shared__ float tile[64][65];
    const float* xs = x + (size_t)blockIdx.z * CDIM * HW;
    bf16* fs = feat + (size_t)blockIdx.z * HW * CDIM;

    int p0 = blockIdx.x * 64;
    int c0 = blockIdx.y * 64;
    int t  = threadIdx.x;

    int pc = t & 63;
    int cr = t >> 6;               // 0..3
#pragma unroll
    for (int i = 0; i < 16; ++i) {
        int cl = cr + i * 4;       // 0..63
        tile[cl][pc] = xs[(size_t)(c0 + cl) * HW + p0 + pc];
    }
    __syncthreads();

    int cc = t & 63;
    int pr = t >> 6;
#pragma unroll
    for (int i = 0; i < 16; ++i) {
        int pl = pr + i * 4;       // 0..63
        fs[(size_t)(p0 + pl) * CDIM + c0 + cc] = __float2bfloat16(tile[cc][pl]);
    }
}

// ---------------------------------------------------------------------------
// Kernel 2: per 128x128 tile of sim = exp(feat1 . feat2^T / T):
//   total += sum(sim), pos += sum(sim where gt1[i]==gt2[j])
// grid = (72, 72), block = 256 (4 waves, each owns a 64x64 quadrant).
// Writes per-block partials {total, pos} to ws (deterministic reduce later).
// ---------------------------------------------------------------------------
__global__ __launch_bounds__(256) void simsum_kernel(const bf16* __restrict__ feat1,
                                                     const bf16* __restrict__ feat2,
                                                     const int* __restrict__ label,
                                                     float* __restrict__ partials) {
    __shared__ bf16 As[BM][LDP];
    __shared__ bf16 Bs[BN][LDP];
    __shared__ int  lg1[BM];
    __shared__ int  lg2[BN];
    __shared__ float red[8];

    int t  = threadIdx.x;
    int i0 = blockIdx.x * BM;
    int j0 = blockIdx.y * BN;

    // labels: gt1 = label[0,0,:,:], gt2 = label[1,0,:,:]
    if (t < BM)       lg1[t] = label[i0 + t];
    else              lg2[t - BM] = label[HW + j0 + (t - BM)];

    // stage A,B tiles: 16B per thread per row-chunk, coalesced 256B rows
    {
        int r  = t >> 4;             // 0..15
        int c8 = (t & 15) * 8;       // bf16 col offset
#pragma unroll
        for (int rr = r; rr < BM; rr += 16) {
            s16x8 va = *(const s16x8*)(&feat1[(size_t)(i0 + rr) * CDIM + c8]);
            *(s16x8*)(&As[rr][c8]) = va;
            s16x8 vb = *(const s16x8*)(&feat2[(size_t)(j0 + rr) * CDIM + c8]);
            *(s16x8*)(&Bs[rr][c8]) = vb;
        }
    }
    __syncthreads();

    int w    = t >> 6;            // wave 0..3
    int lane = t & 63;
    int wr   = w >> 1;            // wave row 0..1  (64-row half)
    int wc   = w & 1;             // wave col 0..1  (64-col half)
    int lr   = lane & 15;         // fragment row/col lane index
    int kg   = lane >> 4;         // 0..3 k-subgroup

    f32x4 acc[4][4] = {};
#pragma unroll
    for (int ks = 0; ks < 4; ++ks) {
        int kbase = ks * 32 + kg * 8;
        s16x8 af[4], bfv[4];
#pragma unroll
        for (int m = 0; m < 4; ++m)
            af[m] = *(const s16x8*)(&As[wr * 64 + m * 16 + lr][kbase]);
#pragma unroll
        for (int n = 0; n < 4; ++n)
            bfv[n] = *(const s16x8*)(&Bs[wc * 64 + n * 16 + lr][kbase]);
#pragma unroll
        for (int m = 0; m < 4; ++m)
#pragma unroll
            for (int n = 0; n < 4; ++n)
                acc[m][n] = __builtin_amdgcn_mfma_f32_16x16x32_bf16(af[m], bfv[n], acc[m][n], 0, 0, 0);
    }

    // C/D layout (m89-verified): col = lane&15, row = (lane>>4)*4 + reg
    int g1v[4][4];
#pragma unroll
    for (int m = 0; m < 4; ++m)
#pragma unroll
        for (int r2 = 0; r2 < 4; ++r2)
            g1v[m][r2] = lg1[wr * 64 + m * 16 + kg * 4 + r2];
    int g2v[4];
#pragma unroll
    for (int n = 0; n < 4; ++n)
        g2v[n] = lg2[wc * 64 + n * 16 + lr];

    float tot = 0.f, pos = 0.f;
#pragma unroll
    for (int m = 0; m < 4; ++m) {
#pragma unroll
        for (int n = 0; n < 4; ++n) {
#pragma unroll
            for (int r2 = 0; r2 < 4; ++r2) {
                float e = exp2f(acc[m][n][r2] * EXP_SCALE);
                tot += e;
                pos += (g1v[m][r2] == g2v[n]) ? e : 0.f;
            }
        }
    }

    // wave reduce
#pragma unroll
    for (int off = 32; off; off >>= 1) {
        tot += __shfl_down(tot, off);
        pos += __shfl_down(pos, off);
    }
    if (lane == 0) { red[w * 2] = tot; red[w * 2 + 1] = pos; }
    __syncthreads();
    if (t == 0) {
        float T4 = red[0] + red[2] + red[4] + red[6];
        float P4 = red[1] + red[3] + red[5] + red[7];
        int bid = blockIdx.y * gridDim.x + blockIdx.x;
        partials[bid * 2]     = T4;
        partials[bid * 2 + 1] = P4;
    }
}

// ---------------------------------------------------------------------------
// Kernel 3: reduce 5184 partial pairs, loss = -log(pos/tot)/hw^2
// ---------------------------------------------------------------------------
__global__ __launch_bounds__(256) void finalize_kernel(const float* __restrict__ partials,
                                                       float* __restrict__ out) {
    double tot = 0.0, pos = 0.0;
    int t = threadIdx.x;
    for (int i = t; i < NBLK; i += 256) {
        tot += (double)partials[i * 2];
        pos += (double)partials[i * 2 + 1];
    }
#pragma unroll
    for (int off = 32; off; off >>= 1) {
        tot += __shfl_down(tot, off);
        pos += __shfl_down(pos, off);
    }
    __shared__ double rt[4], rp[4];
    int w = t >> 6, lane = t & 63;
    if (lane == 0) { rt[w] = tot; rp[w] = pos; }
    __syncthreads();
    if (t == 0) {
        double T = rt[0] + rt[1] + rt[2] + rt[3];
        double P = rp[0] + rp[1] + rp[2] + rp[3];
        double hw2 = (double)HW * (double)HW;
        out[0] = (float)(-log(P / T) / hw2);
    }
}

extern "C" void kernel_launch(void* const* d_in, const int* in_sizes, int n_in,
                              void* d_out, int out_size, void* d_ws, size_t ws_size,
                              hipStream_t stream) {
    const float* x     = (const float*)d_in[0];   // (4,128,96,96) f32; only b=0,1 used
    const int*   label = (const int*)d_in[1];     // (4,1,96,96) i32; only b=0,1 used
    float*       out   = (float*)d_out;

    bf16*  feat  = (bf16*)d_ws;                       // feat1 then feat2, [HW][C] each
    float* parts = (float*)((char*)d_ws + 2 * (size_t)HW * CDIM * sizeof(bf16));

    dim3 g1(HW / 64, CDIM / 64, 2);
    prep_kernel<<<g1, 256, 0, stream>>>(x, feat);

    dim3 g2(HW / BM, HW / BN);
    simsum_kernel<<<g2, 256, 0, stream>>>(feat, feat + (size_t)HW * CDIM, label, parts);

    finalize_kernel<<<1, 256, 0, stream>>>(parts, out);
}

// Round 2
// 60.752 us; speedup vs baseline: 1.1107x; 1.1107x over previous
//
#include <hip/hip_runtime.h>
#include <hip/hip_bf16.h>

#define HW 9216
#define CDIM 128
#define BM 128          // rows per block (band)
#define BN 128          // cols per j-tile
#define JT 4            // j-tiles per block
#define NJG (HW / BN / JT)            // 18
#define NBLK ((HW / BM) * NJG)        // 72*18 = 1296
#define LDP (CDIM + 8)  // padded LDS row stride (bf16): 272B rows -> <=2-way bank alias

using bf16 = __hip_bfloat16;
typedef __attribute__((ext_vector_type(4))) float f32x4;
typedef __attribute__((ext_vector_type(8))) short s16x8;

// exp(d / 0.04) = exp2(d * log2(e)/0.04); scale folded into feat1 at prep time
#define EXP_SCALE 36.067376022224085f

// ---------------------------------------------------------------------------
// Kernel 1: x[b] layout [C][HW] f32 -> feat[b] layout [HW][C] bf16.
// feat1 (b==0) is pre-scaled by EXP_SCALE so simsum's exp arg is the raw MFMA
// accumulator. 64x64 LDS tile transpose. grid=(HW/64, C/64, 2), block=256.
// ---------------------------------------------------------------------------
__global__ __launch_bounds__(256) void prep_kernel(const float* __restrict__ x,
                                                   bf16* __restrict__ feat) {
    __shared__ float tile[64][65];
    const float* xs = x + (size_t)blockIdx.z * CDIM * HW;
    bf16* fs = feat + (size_t)blockIdx.z * HW * CDIM;
    float scale = (blockIdx.z == 0) ? EXP_SCALE : 1.0f;

    int p0 = blockIdx.x * 64;
    int c0 = blockIdx.y * 64;
    int t  = threadIdx.x;

    int pc = t & 63;
    int cr = t >> 6;
#pragma unroll
    for (int i = 0; i < 16; ++i) {
        int cl = cr + i * 4;
        tile[cl][pc] = xs[(size_t)(c0 + cl) * HW + p0 + pc];
    }
    __syncthreads();

    int cc = t & 63;
    int pr = t >> 6;
#pragma unroll
    for (int i = 0; i < 16; ++i) {
        int pl = pr + i * 4;
        fs[(size_t)(p0 + pl) * CDIM + c0 + cc] = __float2bfloat16(tile[cc][pl] * scale);
    }
}

// ---------------------------------------------------------------------------
// Kernel 2: block = 128-row band of feat1 (A frags in registers) x 4 j-tiles.
// Per j-tile: stage B in LDS, MFMA 128x128, exp + masked/total accumulate.
// 4 waves; wave w owns rows [i0+w*32, +32): acc[2 m][8 n] 16x16 fragments.
// grid = (72, 18), block = 256. Partials {tot,pos} per block -> ws.
// ---------------------------------------------------------------------------
__global__ __launch_bounds__(256, 3) void simsum_kernel(const bf16* __restrict__ feat1,
                                                        const bf16* __restrict__ feat2,
                                                        const int* __restrict__ label,
                                                        float* __restrict__ partials) {
    __shared__ bf16 Bs[BN][LDP];
    __shared__ float red[8];

    int t    = threadIdx.x;
    int w    = t >> 6;
    int lane = t & 63;
    int lr   = lane & 15;        // fragment row/col lane index
    int kg   = lane >> 4;        // 0..3 k-subgroup

    int i0  = blockIdx.x * BM;
    int jg0 = blockIdx.y * JT;   // first j-tile index

    // A fragments, persistent in registers: af[m][ks]
    s16x8 af[2][4];
#pragma unroll
    for (int m = 0; m < 2; ++m) {
        int row = i0 + w * 32 + m * 16 + lr;
#pragma unroll
        for (int ks = 0; ks < 4; ++ks)
            af[m][ks] = *(const s16x8*)(&feat1[(size_t)row * CDIM + ks * 32 + kg * 8]);
    }

    // row labels for this wave's accumulator rows: row = .. + kg*4 + r2
    int g1v[2][4];
#pragma unroll
    for (int m = 0; m < 2; ++m)
#pragma unroll
        for (int r2 = 0; r2 < 4; ++r2)
            g1v[m][r2] = label[i0 + w * 32 + m * 16 + kg * 4 + r2];

    float tot = 0.f, pos = 0.f;

    int sr = t >> 4;             // staging row group 0..15
    int c8 = (t & 15) * 8;       // staging bf16 col offset

    for (int jt = 0; jt < JT; ++jt) {
        int j0 = (jg0 + jt) * BN;

        // column labels for this tile (L1-broadcast friendly)
        int g2v[8];
#pragma unroll
        for (int n = 0; n < 8; ++n)
            g2v[n] = label[HW + j0 + n * 16 + lr];

        // stage B tile
#pragma unroll
        for (int rr = sr; rr < BN; rr += 16)
            *(s16x8*)(&Bs[rr][c8]) = *(const s16x8*)(&feat2[(size_t)(j0 + rr) * CDIM + c8]);
        __syncthreads();

        f32x4 acc[2][8] = {};
#pragma unroll
        for (int ks = 0; ks < 4; ++ks) {
            int kbase = ks * 32 + kg * 8;
            s16x8 bfv[8];
#pragma unroll
            for (int n = 0; n < 8; ++n)
                bfv[n] = *(const s16x8*)(&Bs[n * 16 + lr][kbase]);
#pragma unroll
            for (int m = 0; m < 2; ++m)
#pragma unroll
                for (int n = 0; n < 8; ++n)
                    acc[m][n] = __builtin_amdgcn_mfma_f32_16x16x32_bf16(af[m][ks], bfv[n], acc[m][n], 0, 0, 0);
        }
        __syncthreads();   // Bs consumed; next iteration may restage

        // exp + accumulate (feat1 pre-scaled: arg = acc directly)
#pragma unroll
        for (int m = 0; m < 2; ++m) {
#pragma unroll
            for (int n = 0; n < 8; ++n) {
#pragma unroll
                for (int r2 = 0; r2 < 4; ++r2) {
                    float e = exp2f(acc[m][n][r2]);
                    tot += e;
                    pos += (g1v[m][r2] == g2v[n]) ? e : 0.f;
                }
            }
        }
    }

    // wave reduce
#pragma unroll
    for (int off = 32; off; off >>= 1) {
        tot += __shfl_down(tot, off);
        pos += __shfl_down(pos, off);
    }
    if (lane == 0) { red[w * 2] = tot; red[w * 2 + 1] = pos; }
    __syncthreads();
    if (t == 0) {
        float T4 = red[0] + red[2] + red[4] + red[6];
        float P4 = red[1] + red[3] + red[5] + red[7];
        int bid = blockIdx.y * gridDim.x + blockIdx.x;
        partials[bid * 2]     = T4;
        partials[bid * 2 + 1] = P4;
    }
}

// ---------------------------------------------------------------------------
// Kernel 3: reduce partial pairs, loss = -log(pos/tot)/hw^2
// ---------------------------------------------------------------------------
__global__ __launch_bounds__(256) void finalize_kernel(const float* __restrict__ partials,
                                                       float* __restrict__ out) {
    double tot = 0.0, pos = 0.0;
    int t = threadIdx.x;
    for (int i = t; i < NBLK; i += 256) {
        tot += (double)partials[i * 2];
        pos += (double)partials[i * 2 + 1];
    }
#pragma unroll
    for (int off = 32; off; off >>= 1) {
        tot += __shfl_down(tot, off);
        pos += __shfl_down(pos, off);
    }
    __shared__ double rt[4], rp[4];
    int w = t >> 6, lane = t & 63;
    if (lane == 0) { rt[w] = tot; rp[w] = pos; }
    __syncthreads();
    if (t == 0) {
        double T = rt[0] + rt[1] + rt[2] + rt[3];
        double P = rp[0] + rp[1] + rp[2] + rp[3];
        double hw2 = (double)HW * (double)HW;
        out[0] = (float)(-log(P / T) / hw2);
    }
}

extern "C" void kernel_launch(void* const* d_in, const int* in_sizes, int n_in,
                              void* d_out, int out_size, void* d_ws, size_t ws_size,
                              hipStream_t stream) {
    const float* x     = (const float*)d_in[0];   // (4,128,96,96) f32; only b=0,1 used
    const int*   label = (const int*)d_in[1];     // (4,1,96,96) i32; only b=0,1 used
    float*       out   = (float*)d_out;

    bf16*  feat  = (bf16*)d_ws;                       // feat1 (pre-scaled), feat2
    float* parts = (float*)((char*)d_ws + 2 * (size_t)HW * CDIM * sizeof(bf16));

    dim3 g1(HW / 64, CDIM / 64, 2);
    prep_kernel<<<g1, 256, 0, stream>>>(x, feat);

    dim3 g2(HW / BM, NJG);
    simsum_kernel<<<g2, 256, 0, stream>>>(feat, feat + (size_t)HW * CDIM, label, parts);

    finalize_kernel<<<1, 256, 0, stream>>>(parts, out);
}